// Round 12
// baseline (281.910 us; speedup 1.0000x reference)
//
#include <hip/hip_runtime.h>
#include <math.h>

// ---------------------------------------------------------------------------
// EEG StandAlone Attention stem — 7-launch fused pipeline.
// K1 stage0: inline prep0 + fused score/softmax/value + analytic BN stats
//    + role blocks building G1, Wy1, embs1, Wcat2 (all weight prep).
// K2a attn1: G-trick scores (u=G^T.xbn in LDS), self-finalizes BN0.
// K2b gemm_y: y[m,o,n] = vw.BN(x) (M=512,K=64 GEMM, BN fused, self-final).
//    (split from round-11's merged kernel: the union LDS footprint halved
//     the GEMM's occupancy — separate launches restore natural footprints.)
// K3 combine1: out = sum_{m,t} attn*emb*y_shift -> h1raw + part1.
// K4 gemm2: qk+z GEMM (self-finalizes BN1 stats from part1).
// K5 attn+combine2 fused. K6 final BN+ReLU+AvgPool.
// ---------------------------------------------------------------------------

#define TPB 256

// ==== K1: stage0 + weight prep ==============================================
__global__ void stage0_kernel(const float* __restrict__ x,    // [2][8][3000]
                              const float* __restrict__ qw0, const float* __restrict__ kw0,
                              const float* __restrict__ vw0, const float* __restrict__ ea0,
                              const float* __restrict__ eb0, const float* __restrict__ em0,
                              const float* __restrict__ qw1, const float* __restrict__ kw1,
                              const float* __restrict__ vw1, const float* __restrict__ ea1,
                              const float* __restrict__ eb1, const float* __restrict__ em1,
                              const float* __restrict__ qw2, const float* __restrict__ kw2,
                              const float* __restrict__ vw2, const float* __restrict__ ea2,
                              const float* __restrict__ eb2, const float* __restrict__ em2,
                              float* __restrict__ h0raw,      // [2][64][6000]
                              float2* __restrict__ part0,     // [64][188]
                              float* __restrict__ G,          // [64][64]
                              float* __restrict__ Wy,         // [512][64]
                              float* __restrict__ embs1g,     // [40]
                              float* __restrict__ Wcat2) {    // [192][128]
    int tid = threadIdx.x;
    int bx = blockIdx.x;
    if (bx >= 94) {
        if (blockIdx.y != 0 || blockIdx.z != 0) return;
        int role = bx - 94;
        __shared__ float la[8], lb[20], embs[40];
        if (role == 0) {
            if (tid < 8) {
                int m = tid / 2, k = tid % 2;
                float s = 0.f;
                for (int o = 0; o < 128; ++o) s += em1[m * 128 + o] * ea1[o * 2 + k];
                la[tid] = s;
            }
            if (tid >= 64 && tid < 84) {
                int r = tid - 64;
                int m = r / 5, l = r % 5;
                float s = 0.f;
                for (int o = 0; o < 128; ++o) s += em1[m * 128 + o] * eb1[o * 5 + l];
                lb[r] = s;
            }
            __syncthreads();
            if (tid < 10) {
                int k = tid / 5, l = tid % 5;
                float lg[4], mx = -1e30f;
                for (int m = 0; m < 4; ++m) {
                    lg[m] = la[m * 2 + k] + lb[m * 5 + l];
                    mx = fmaxf(mx, lg[m]);
                }
                float sum = 0.f;
                for (int m = 0; m < 4; ++m) { lg[m] = expf(lg[m] - mx); sum += lg[m]; }
                float inv = 1.f / sum;
                for (int m = 0; m < 4; ++m) embs[tid * 4 + m] = lg[m] * inv;
            }
            __syncthreads();
            if (tid < 40) embs1g[tid] = embs[tid];
            for (int e = tid; e < 2048; e += 256) {
                int c = e >> 6, c2 = e & 63;
                float s = 0.f;
                for (int o = 0; o < 128; ++o)
                    s = fmaf(qw1[c * 128 + o], kw1[c2 * 128 + o], s);
                G[e] = s;
            }
        } else if (role == 1) {
            for (int e = 2048 + tid; e < 4096; e += 256) {
                int c = e >> 6, c2 = e & 63;
                float s = 0.f;
                for (int o = 0; o < 128; ++o)
                    s = fmaf(qw1[c * 128 + o], kw1[c2 * 128 + o], s);
                G[e] = s;
            }
        } else if (role == 2 || role == 3) {
            int base = (role - 2) * 16384;
            for (int e = base + tid; e < base + 16384; e += 256) {
                int r = e >> 6, c = e & 63;
                int m = r >> 7, o = r & 127;
                Wy[e] = vw1[(m * 64 + c) * 128 + o];
            }
        } else {
            if (tid < 8) {
                int m = tid / 2, k = tid % 2;
                float s = 0.f;
                for (int o = 0; o < 16; ++o) s += em2[m * 16 + o] * ea2[o * 2 + k];
                la[tid] = s;
            }
            if (tid >= 64 && tid < 84) {
                int r = tid - 64;
                int m = r / 5, l = r % 5;
                float s = 0.f;
                for (int o = 0; o < 16; ++o) s += em2[m * 16 + o] * eb2[o * 5 + l];
                lb[r] = s;
            }
            __syncthreads();
            if (tid < 10) {
                int k = tid / 5, l = tid % 5;
                float lg[4], mx = -1e30f;
                for (int m = 0; m < 4; ++m) {
                    lg[m] = la[m * 2 + k] + lb[m * 5 + l];
                    mx = fmaxf(mx, lg[m]);
                }
                float sum = 0.f;
                for (int m = 0; m < 4; ++m) { lg[m] = expf(lg[m] - mx); sum += lg[m]; }
                float inv = 1.f / sum;
                for (int m = 0; m < 4; ++m) embs[tid * 4 + m] = lg[m] * inv;
            }
            __syncthreads();
            int base = (role - 4) * 6144;
            for (int e = base + tid; e < base + 6144; e += 256) {
                int row = e >> 7, c = e & 127;
                float val;
                if (row < 16) {
                    val = qw2[c * 16 + row];
                } else if (row < 32) {
                    val = kw2[c * 16 + (row - 16)];
                } else {
                    int t = (row - 32) >> 4, o = (row - 32) & 15;
                    val = 0.f;
                    for (int m = 0; m < 4; ++m)
                        val += embs[t * 4 + m] * vw2[(m * 128 + c) * 16 + o];
                }
                Wcat2[e] = val;
            }
        }
        return;
    }
    // ---- main stage0 role ----
    __shared__ float wsh[5][256];
    __shared__ float vsh[320];
    __shared__ float wred[4][20];
    __shared__ float wfin[20];
    __shared__ float la0[4], lb0[20], embs0[20];
    __shared__ float c0s;
    int b = blockIdx.y;
    int oz = blockIdx.z;
    int n0 = bx * 256;
    int n = n0 + tid;
    if (tid < 64) {
        float p = qw0[tid] * kw0[tid];
#pragma unroll
        for (int d = 1; d < 64; d <<= 1) p += __shfl_xor(p, d, 64);
        if (tid == 0) c0s = p;
    }
    if (tid >= 64 && tid < 68) {
        int m = tid - 64;
        float s = 0.f;
        for (int o = 0; o < 64; ++o) s += em0[m * 64 + o] * ea0[o];
        la0[m] = s;
    }
    if (tid >= 128 && tid < 148) {
        int r = tid - 128;
        int m = r / 5, l = r % 5;
        float s = 0.f;
        for (int o = 0; o < 64; ++o) s += em0[m * 64 + o] * eb0[o * 5 + l];
        lb0[m * 5 + l] = s;
    }
    __syncthreads();
    if (tid < 5) {
        float lg[4], mx = -1e30f;
        for (int m = 0; m < 4; ++m) {
            lg[m] = la0[m] + lb0[m * 5 + tid];
            mx = fmaxf(mx, lg[m]);
        }
        float sum = 0.f;
        for (int m = 0; m < 4; ++m) { lg[m] = expf(lg[m] - mx); sum += lg[m]; }
        float inv = 1.f / sum;
        for (int m = 0; m < 4; ++m) embs0[tid * 4 + m] = lg[m] * inv;
    }
    __syncthreads();
    for (int e = tid; e < 320; e += 256) {
        int t = e / 64, o = e - t * 64;
        float s = 0.f;
        for (int m = 0; m < 4; ++m) s += embs0[t * 4 + m] * vw0[m * 64 + o];
        vsh[e] = s;
    }
    __syncthreads();
    float c0 = c0s;
    float warr[5];
    if (n < 24000) {
        int h = n / 3000, w = n - h * 3000;
        const float* xr = x + b * 24000 + h * 3000;
        float xc = xr[w];
        float xs[5], s[5];
#pragma unroll
        for (int t = 0; t < 5; ++t) {
            int col = w + t - 2;
            xs[t] = (col >= 0 && col < 3000) ? xr[col] : 0.f;
            s[t] = c0 * xc * xs[t];
        }
        float mx = s[0];
#pragma unroll
        for (int t = 1; t < 5; ++t) mx = fmaxf(mx, s[t]);
        float sum = 0.f;
#pragma unroll
        for (int t = 0; t < 5; ++t) { s[t] = expf(s[t] - mx); sum += s[t]; }
        float inv = 1.f / sum;
#pragma unroll
        for (int t = 0; t < 5; ++t) warr[t] = s[t] * inv * xs[t];
    } else {
#pragma unroll
        for (int t = 0; t < 5; ++t) warr[t] = 0.f;
    }
#pragma unroll
    for (int t = 0; t < 5; ++t) wsh[t][tid] = warr[t];
    float p[20];
#pragma unroll
    for (int t = 0; t < 5; ++t) p[t] = warr[t];
    {
        int k = 5;
#pragma unroll
        for (int t = 0; t < 5; ++t)
#pragma unroll
            for (int t2 = t; t2 < 5; ++t2) p[k++] = warr[t] * warr[t2];
    }
#pragma unroll
    for (int d = 1; d < 64; d <<= 1)
#pragma unroll
        for (int i = 0; i < 20; ++i) p[i] += __shfl_xor(p[i], d, 64);
    if ((tid & 63) == 0)
#pragma unroll
        for (int i = 0; i < 20; ++i) wred[tid >> 6][i] = p[i];
    __syncthreads();
    if (tid < 20)
        wfin[tid] = wred[0][tid] + wred[1][tid] + wred[2][tid] + wred[3][tid];
    __syncthreads();
    int jq = tid & 63, og = tid >> 6;
    int nq = n0 + jq * 4;
    int h = nq / 3000, w0 = nq - h * 3000;
    bool st = (nq < 24000) && ((h & 1) == 0);
    float wq[5][4];
#pragma unroll
    for (int t = 0; t < 5; ++t)
#pragma unroll
        for (int j = 0; j < 4; ++j) wq[t][j] = wsh[t][jq * 4 + j];
    int obase = oz * 32 + og * 8;
    for (int oi = 0; oi < 8; ++oi) {
        int o = obase + oi;
        float4 v = make_float4(0.f, 0.f, 0.f, 0.f);
#pragma unroll
        for (int t = 0; t < 5; ++t) {
            float vo = vsh[t * 64 + o];
            v.x = fmaf(wq[t][0], vo, v.x);
            v.y = fmaf(wq[t][1], vo, v.y);
            v.z = fmaf(wq[t][2], vo, v.z);
            v.w = fmaf(wq[t][3], vo, v.w);
        }
        if (st) {
            size_t base = ((size_t)b * 64 + o) * 6000 + (h >> 1) * 1500 + (w0 >> 1);
            *(float2*)&h0raw[base] = make_float2(v.x, v.z);
        }
    }
    if (tid < 32) {
        int o = oz * 32 + tid;
        float vt[5];
#pragma unroll
        for (int t = 0; t < 5; ++t) vt[t] = vsh[t * 64 + o];
        float s = 0.f, s2 = 0.f;
#pragma unroll
        for (int t = 0; t < 5; ++t) s = fmaf(vt[t], wfin[t], s);
        int k = 5;
#pragma unroll
        for (int t = 0; t < 5; ++t)
#pragma unroll
            for (int t2 = t; t2 < 5; ++t2) {
                float coef = (t == t2) ? vt[t] * vt[t] : 2.f * vt[t] * vt[t2];
                s2 = fmaf(coef, wfin[k], s2);
                ++k;
            }
        int chunk = b * 94 + bx;
        part0[(size_t)o * 188 + chunk] = make_float2(s, s2);
    }
}

// ==== K2a: stage1 attention (self-finalizes BN0) ============================
__global__ void attn1_kernel(const float* __restrict__ G,     // [64][64]
                             const float* __restrict__ xraw,  // [b][64][6000]
                             const float2* __restrict__ part0,
                             const float* __restrict__ g0,
                             const float* __restrict__ b0,
                             float* __restrict__ attn) {      // [b][10][6000]
    __shared__ float xw[64][2][68];
    __shared__ float gbuf[64][64];
    __shared__ float ssh[64][12];
    __shared__ float scb[64], sfb[64];
    int tid = threadIdx.x;
    int chunk = blockIdx.x;
    int ho = blockIdx.y;
    int b = blockIdx.z;
    int wo0 = chunk * 64;
    if (tid < 64) {
        double s = 0.0, s2 = 0.0;
        const float2* pp = part0 + (size_t)tid * 188;
        for (int i = 0; i < 188; ++i) { float2 p = pp[i]; s += p.x; s2 += p.y; }
        double mean = s / 48000.0;
        double var = s2 / 48000.0 - mean * mean;
        float rstd = (float)(1.0 / sqrt(var + 1e-5));
        float sc = rstd * g0[tid];
        scb[tid] = sc;
        sfb[tid] = b0[tid] - (float)mean * sc;
    }
    for (int e = tid; e < 4096; e += 256)
        gbuf[e >> 6][e & 63] = G[e];
    __syncthreads();
    for (int e = tid; e < 64 * 136; e += 256) {
        int c = e / 136;
        int r2 = e - c * 136;
        int r = r2 / 68, jj = r2 - r * 68;
        int row = ho - 1 + r;
        int col = wo0 + jj - 2;
        float v = 0.f;
        if (row >= 0 && col >= 0 && col < 1500) {
            float xv = xraw[((size_t)b * 64 + c) * 6000 + row * 1500 + col];
            v = fmaxf(fmaf(xv, scb[c], sfb[c]), 0.f);
        }
        xw[c][r][jj] = v;
    }
    __syncthreads();
    int j = tid & 63, cg = tid >> 6;
    float ul[16];
#pragma unroll
    for (int i = 0; i < 16; ++i) ul[i] = 0.f;
    for (int c = 0; c < 64; ++c) {
        float xv = xw[c][1][j + 2];
        float4 q0 = *(const float4*)&gbuf[c][cg * 16 + 0];
        float4 q1 = *(const float4*)&gbuf[c][cg * 16 + 4];
        float4 q2 = *(const float4*)&gbuf[c][cg * 16 + 8];
        float4 q3 = *(const float4*)&gbuf[c][cg * 16 + 12];
        ul[0]  = fmaf(q0.x, xv, ul[0]);  ul[1]  = fmaf(q0.y, xv, ul[1]);
        ul[2]  = fmaf(q0.z, xv, ul[2]);  ul[3]  = fmaf(q0.w, xv, ul[3]);
        ul[4]  = fmaf(q1.x, xv, ul[4]);  ul[5]  = fmaf(q1.y, xv, ul[5]);
        ul[6]  = fmaf(q1.z, xv, ul[6]);  ul[7]  = fmaf(q1.w, xv, ul[7]);
        ul[8]  = fmaf(q2.x, xv, ul[8]);  ul[9]  = fmaf(q2.y, xv, ul[9]);
        ul[10] = fmaf(q2.z, xv, ul[10]); ul[11] = fmaf(q2.w, xv, ul[11]);
        ul[12] = fmaf(q3.x, xv, ul[12]); ul[13] = fmaf(q3.y, xv, ul[13]);
        ul[14] = fmaf(q3.z, xv, ul[14]); ul[15] = fmaf(q3.w, xv, ul[15]);
    }
    __syncthreads();
#pragma unroll
    for (int i = 0; i < 16; ++i) gbuf[cg * 16 + i][j] = ul[i];
    __syncthreads();
    int t0 = cg, t1 = cg + 4, t2 = cg + 8;
    int dk0 = t0 / 5, dl0 = t0 % 5;
    int dk1 = t1 / 5, dl1 = t1 % 5;
    int dk2 = (t2 < 10) ? 1 : 0, dl2 = (t2 < 10) ? (t2 - 5) : 0;
    float s0 = 0.f, s1 = 0.f, s2v = 0.f;
    for (int c = 0; c < 64; ++c) {
        float uv = gbuf[c][j];
        s0 = fmaf(uv, xw[c][dk0][j + dl0], s0);
        s1 = fmaf(uv, xw[c][dk1][j + dl1], s1);
        if (t2 < 10) s2v = fmaf(uv, xw[c][dk2][j + dl2], s2v);
    }
    ssh[j][t0] = s0;
    ssh[j][t1] = s1;
    if (t2 < 10) ssh[j][t2] = s2v;
    __syncthreads();
    if (tid < 64 && wo0 + tid < 1500) {
        float sc[10];
        float mx = -1e30f;
#pragma unroll
        for (int t = 0; t < 10; ++t) { sc[t] = ssh[tid][t]; mx = fmaxf(mx, sc[t]); }
        float sum = 0.f;
#pragma unroll
        for (int t = 0; t < 10; ++t) { sc[t] = expf(sc[t] - mx); sum += sc[t]; }
        float inv = 1.f / sum;
        int n = ho * 1500 + wo0 + tid;
#pragma unroll
        for (int t = 0; t < 10; ++t)
            attn[((size_t)b * 10 + t) * 6000 + n] = sc[t] * inv;
    }
}

// ==== K2b: y-GEMM (M=512, K=64, BN fused, self-finalizes BN0) ===============
__launch_bounds__(256, 4)
__global__ void gemm_y_kernel(const float* __restrict__ Wy,    // [512][64]
                              const float* __restrict__ xraw,  // [b][64][6000]
                              const float2* __restrict__ part0,
                              const float* __restrict__ g0,
                              const float* __restrict__ b0,
                              float* __restrict__ ybuf) {      // [b][512][6000]
    __shared__ float As[32][132];
    __shared__ float Bs[32][132];
    __shared__ float scale[64], shift[64];
    int tid = threadIdx.x;
    int b = blockIdx.z;
    int m0 = blockIdx.y * 128, n0 = blockIdx.x * 128;
    if (tid < 64) {
        double s = 0.0, s2 = 0.0;
        const float2* pp = part0 + (size_t)tid * 188;
        for (int i = 0; i < 188; ++i) { float2 p = pp[i]; s += p.x; s2 += p.y; }
        double mean = s / 48000.0;
        double var = s2 / 48000.0 - mean * mean;
        float rstd = (float)(1.0 / sqrt(var + 1e-5));
        float sc = rstd * g0[tid];
        scale[tid] = sc;
        shift[tid] = b0[tid] - (float)mean * sc;
    }
    __syncthreads();
    float acc[8][8] = {{0.f}};
    int am = tid >> 1, ak = (tid & 1) * 16;
    int bk = tid >> 3, bn = (tid & 7) * 16;
    int tm = tid & 15, tn = tid >> 4;
    for (int k0 = 0; k0 < 64; k0 += 32) {
        {
            const float* Ap = Wy + (size_t)(m0 + am) * 64 + k0 + ak;
#pragma unroll
            for (int q = 0; q < 4; ++q) {
                float4 v = *(const float4*)(Ap + q * 4);
                int kk = ak + q * 4;
                As[kk + 0][am] = v.x;
                As[kk + 1][am] = v.y;
                As[kk + 2][am] = v.z;
                As[kk + 3][am] = v.w;
            }
        }
        {
            int c = k0 + bk;
            float sc = scale[c], sf = shift[c];
            const float* Xp = xraw + ((size_t)b * 64 + c) * 6000 + n0 + bn;
            if (n0 + 128 <= 6000) {
#pragma unroll
                for (int q = 0; q < 4; ++q) {
                    float4 v = *(const float4*)(Xp + q * 4);
                    v.x = fmaxf(fmaf(v.x, sc, sf), 0.f);
                    v.y = fmaxf(fmaf(v.y, sc, sf), 0.f);
                    v.z = fmaxf(fmaf(v.z, sc, sf), 0.f);
                    v.w = fmaxf(fmaf(v.w, sc, sf), 0.f);
                    *(float4*)&Bs[bk][bn + q * 4] = v;
                }
            } else {
#pragma unroll
                for (int q = 0; q < 16; ++q) {
                    int n = n0 + bn + q;
                    Bs[bk][bn + q] = (n < 6000) ? fmaxf(fmaf(Xp[q], sc, sf), 0.f) : 0.f;
                }
            }
        }
        __syncthreads();
#pragma unroll 8
        for (int k = 0; k < 32; ++k) {
            float4 a0 = *(const float4*)&As[k][tm * 4];
            float4 a1 = *(const float4*)&As[k][64 + tm * 4];
            float4 bb0 = *(const float4*)&Bs[k][tn * 4];
            float4 bb1 = *(const float4*)&Bs[k][64 + tn * 4];
            float av[8] = {a0.x, a0.y, a0.z, a0.w, a1.x, a1.y, a1.z, a1.w};
            float bv[8] = {bb0.x, bb0.y, bb0.z, bb0.w, bb1.x, bb1.y, bb1.z, bb1.w};
#pragma unroll
            for (int i = 0; i < 8; ++i)
#pragma unroll
                for (int jx = 0; jx < 8; ++jx)
                    acc[i][jx] = fmaf(av[i], bv[jx], acc[i][jx]);
        }
        __syncthreads();
    }
    bool fullN = (n0 + 128 <= 6000);
#pragma unroll
    for (int iq = 0; iq < 2; ++iq) {
        int mb = m0 + iq * 64 + tm * 4;
#pragma unroll
        for (int i = 0; i < 4; ++i) {
            int row = mb + i;
            float* zp = &ybuf[((size_t)b * 512 + row) * 6000];
#pragma unroll
            for (int jq = 0; jq < 2; ++jq) {
                int nb_ = n0 + jq * 64 + tn * 4;
                if (fullN) {
                    *(float4*)&zp[nb_] = make_float4(acc[iq * 4 + i][jq * 4 + 0],
                                                     acc[iq * 4 + i][jq * 4 + 1],
                                                     acc[iq * 4 + i][jq * 4 + 2],
                                                     acc[iq * 4 + i][jq * 4 + 3]);
                } else {
#pragma unroll
                    for (int jj = 0; jj < 4; ++jj)
                        if (nb_ + jj < 6000) zp[nb_ + jj] = acc[iq * 4 + i][jq * 4 + jj];
                }
            }
        }
    }
}

// ==== K3: combine1 ==========================================================
__global__ void combine1_kernel(const float* __restrict__ y,     // [b][512][6000]
                                const float* __restrict__ attn,  // [b][10][6000]
                                const float* __restrict__ embs1, // [40] t*4+m
                                float* __restrict__ h1raw,       // [b][128][1500]
                                float2* __restrict__ part1) {    // [128][48]
    __shared__ float yw[4][2][256];
    __shared__ float embl[40];
    __shared__ float sh[TPB], sh2[TPB];
    int tid = threadIdx.x;
    int bx = blockIdx.x;
    int ho = bx / 6, wc = bx - ho * 6;
    int wo0 = wc * 250;
    int by = blockIdx.y;
    int b = by >> 7, o = by & 127;
    if (tid < 40) embl[tid] = embs1[tid];
    for (int e = tid; e < 4 * 2 * 256; e += 256) {
        int m = e >> 9;
        int rem = e & 511;
        int r = rem >> 8, j = rem & 255;
        int row = ho - 1 + r;
        int col = wo0 - 2 + j;
        float v = 0.f;
        if (j < 254 && row >= 0 && row < 4 && col >= 0 && col < 1500)
            v = y[((size_t)b * 512 + m * 128 + o) * 6000 + row * 1500 + col];
        yw[m][r][j] = v;
    }
    __syncthreads();
    float val = 0.f;
    int wo = wo0 + tid;
    if (tid < 250) {
        int n = ho * 1500 + wo;
        float a[10];
#pragma unroll
        for (int t = 0; t < 10; ++t)
            a[t] = attn[((size_t)b * 10 + t) * 6000 + n];
#pragma unroll
        for (int m = 0; m < 4; ++m) {
#pragma unroll
            for (int dk = 0; dk < 2; ++dk)
#pragma unroll
                for (int dl = 0; dl < 5; ++dl) {
                    int t = dk * 5 + dl;
                    val = fmaf(a[t] * embl[t * 4 + m], yw[m][dk][tid + dl], val);
                }
        }
        if (((ho | wo) & 1) == 0)
            h1raw[((size_t)b * 128 + o) * 1500 + (ho >> 1) * 750 + (wo >> 1)] = val;
    }
    sh[tid] = (tid < 250) ? val : 0.f;
    sh2[tid] = (tid < 250) ? val * val : 0.f;
    __syncthreads();
    for (int st = TPB / 2; st > 0; st >>= 1) {
        if (tid < st) { sh[tid] += sh[tid + st]; sh2[tid] += sh2[tid + st]; }
        __syncthreads();
    }
    if (tid == 0) {
        int chunk = b * 24 + bx;
        part1[(size_t)o * 48 + chunk] = make_float2(sh[0], sh2[0]);
    }
}

// ==== K4: stage2 qk+z GEMM (self-finalizes BN1) =============================
__launch_bounds__(256, 4)
__global__ void gemm2_kernel(const float* __restrict__ A,     // [192][128]
                             const float* __restrict__ xraw,  // [b][128][1500]
                             const float2* __restrict__ part1,
                             const float* __restrict__ g1,
                             const float* __restrict__ b1,
                             float* __restrict__ qk,          // [b][1500][32]
                             float* __restrict__ z) {         // [b][160][1500]
    const int M = 192, N = 1500, K = 128, twoCo = 32, Mz = 160;
    __shared__ float As[32][132];
    __shared__ float Bs[32][132];
    __shared__ float scale[128], shift[128];
    int tid = threadIdx.x;
    int b = blockIdx.z;
    int m0 = blockIdx.y * 128, n0 = blockIdx.x * 128;
    float acc[8][8] = {{0.f}};
    int am = tid >> 1, ak = (tid & 1) * 16;
    int bk = tid >> 3, bn = (tid & 7) * 16;
    int tm = tid & 15, tn = tid >> 4;
    if (tid < 128) {
        double s = 0.0, s2 = 0.0;
        const float2* pp = part1 + (size_t)tid * 48;
        for (int i = 0; i < 48; ++i) { float2 p = pp[i]; s += p.x; s2 += p.y; }
        double mean = s / 12000.0;
        double var = s2 / 12000.0 - mean * mean;
        float rstd = (float)(1.0 / sqrt(var + 1e-5));
        float sc = rstd * g1[tid];
        scale[tid] = sc;
        shift[tid] = b1[tid] - (float)mean * sc;
    }
    __syncthreads();
    for (int k0 = 0; k0 < K; k0 += 32) {
        {
            int mA = m0 + am;
            const float* Ap = A + (size_t)mA * K + k0 + ak;
#pragma unroll
            for (int q = 0; q < 4; ++q) {
                float4 v = (mA < M) ? *(const float4*)(Ap + q * 4)
                                    : make_float4(0.f, 0.f, 0.f, 0.f);
                int kk = ak + q * 4;
                As[kk + 0][am] = v.x;
                As[kk + 1][am] = v.y;
                As[kk + 2][am] = v.z;
                As[kk + 3][am] = v.w;
            }
        }
        {
            int c = k0 + bk;
            float sc = scale[c], sf = shift[c];
            const float* Xp = xraw + ((size_t)b * K + c) * N + n0 + bn;
            if (n0 + 128 <= N) {
#pragma unroll
                for (int q = 0; q < 4; ++q) {
                    float4 v = *(const float4*)(Xp + q * 4);
                    v.x = fmaxf(fmaf(v.x, sc, sf), 0.f);
                    v.y = fmaxf(fmaf(v.y, sc, sf), 0.f);
                    v.z = fmaxf(fmaf(v.z, sc, sf), 0.f);
                    v.w = fmaxf(fmaf(v.w, sc, sf), 0.f);
                    *(float4*)&Bs[bk][bn + q * 4] = v;
                }
            } else {
#pragma unroll
                for (int q = 0; q < 16; ++q) {
                    int n = n0 + bn + q;
                    Bs[bk][bn + q] = (n < N) ? fmaxf(fmaf(Xp[q], sc, sf), 0.f) : 0.f;
                }
            }
        }
        __syncthreads();
#pragma unroll 8
        for (int k = 0; k < 32; ++k) {
            float4 a0 = *(const float4*)&As[k][tm * 4];
            float4 a1 = *(const float4*)&As[k][64 + tm * 4];
            float4 bb0 = *(const float4*)&Bs[k][tn * 4];
            float4 bb1 = *(const float4*)&Bs[k][64 + tn * 4];
            float av[8] = {a0.x, a0.y, a0.z, a0.w, a1.x, a1.y, a1.z, a1.w};
            float bv[8] = {bb0.x, bb0.y, bb0.z, bb0.w, bb1.x, bb1.y, bb1.z, bb1.w};
#pragma unroll
            for (int i = 0; i < 8; ++i)
#pragma unroll
                for (int jx = 0; jx < 8; ++jx)
                    acc[i][jx] = fmaf(av[i], bv[jx], acc[i][jx]);
        }
        __syncthreads();
    }
    bool fullN = (n0 + 128 <= N);
#pragma unroll
    for (int iq = 0; iq < 2; ++iq) {
        int mb = m0 + iq * 64 + tm * 4;
        if (mb >= M) continue;
        if (mb < twoCo) {
#pragma unroll
            for (int jq = 0; jq < 2; ++jq)
#pragma unroll
                for (int jj = 0; jj < 4; ++jj) {
                    int n = n0 + jq * 64 + tn * 4 + jj;
                    if (n < N) {
                        float4 v = make_float4(acc[iq * 4 + 0][jq * 4 + jj],
                                               acc[iq * 4 + 1][jq * 4 + jj],
                                               acc[iq * 4 + 2][jq * 4 + jj],
                                               acc[iq * 4 + 3][jq * 4 + jj]);
                        *(float4*)&qk[((size_t)b * N + n) * twoCo + mb] = v;
                    }
                }
        } else {
#pragma unroll
            for (int i = 0; i < 4; ++i) {
                int row = mb + i - twoCo;
                float* zp = &z[((size_t)b * Mz + row) * N];
#pragma unroll
                for (int jq = 0; jq < 2; ++jq) {
                    int nb_ = n0 + jq * 64 + tn * 4;
                    if (fullN) {
                        *(float4*)&zp[nb_] = make_float4(acc[iq * 4 + i][jq * 4 + 0],
                                                         acc[iq * 4 + i][jq * 4 + 1],
                                                         acc[iq * 4 + i][jq * 4 + 2],
                                                         acc[iq * 4 + i][jq * 4 + 3]);
                    } else {
#pragma unroll
                        for (int jj = 0; jj < 4; ++jj)
                            if (nb_ + jj < N) zp[nb_ + jj] = acc[iq * 4 + i][jq * 4 + jj];
                    }
                }
            }
        }
    }
}

// ==== K5: stage2 attn + combine + stats fused ===============================
__global__ void attn_combine2_kernel(const float* __restrict__ qk, // [b][1500][32]
                                     const float* __restrict__ z,  // [b][160][1500]
                                     float* __restrict__ out,      // [b][16][750]
                                     float2* __restrict__ part) {  // [16][6]
    __shared__ float sh[TPB], sh2[TPB];
    int tid = threadIdx.x;
    int bx = blockIdx.x;
    int by = blockIdx.y;
    int b = by >> 4, o = by & 15;
    int n = bx * 256 + tid;
    float val = 0.f;
    if (n < 750) {
        const float* qp = qk + ((size_t)b * 1500 + n) * 32;
        float q[16];
#pragma unroll
        for (int i = 0; i < 16; i += 4) {
            float4 v = *(const float4*)(qp + i);
            q[i] = v.x; q[i + 1] = v.y; q[i + 2] = v.z; q[i + 3] = v.w;
        }
        float s[10];
        bool valid[10];
        int col[10];
#pragma unroll
        for (int dk = 0; dk < 2; ++dk)
#pragma unroll
            for (int dl = 0; dl < 5; ++dl) {
                int t = dk * 5 + dl;
                int c = n + dl - 2;
                valid[t] = (c >= 0 && c < 750);
                col[t] = dk * 750 + c;
                float sv = 0.f;
                if (valid[t]) {
                    const float* kp = qk + ((size_t)b * 1500 + col[t]) * 32 + 16;
#pragma unroll
                    for (int i = 0; i < 16; i += 4) {
                        float4 k4 = *(const float4*)(kp + i);
                        sv += q[i] * k4.x + q[i + 1] * k4.y + q[i + 2] * k4.z + q[i + 3] * k4.w;
                    }
                }
                s[t] = sv;
            }
        float mx = s[0];
#pragma unroll
        for (int t = 1; t < 10; ++t) mx = fmaxf(mx, s[t]);
        float sum = 0.f;
#pragma unroll
        for (int t = 0; t < 10; ++t) { s[t] = expf(s[t] - mx); sum += s[t]; }
        float inv = 1.f / sum;
#pragma unroll
        for (int t = 0; t < 10; ++t) {
            if (valid[t]) {
                float zv = z[((size_t)b * 160 + t * 16 + o) * 1500 + col[t]];
                val = fmaf(s[t] * inv, zv, val);
            }
        }
        out[((size_t)b * 16 + o) * 750 + n] = val;
    }
    sh[tid] = (n < 750) ? val : 0.f;
    sh2[tid] = (n < 750) ? val * val : 0.f;
    __syncthreads();
    for (int st = TPB / 2; st > 0; st >>= 1) {
        if (tid < st) { sh[tid] += sh[tid + st]; sh2[tid] += sh2[tid + st]; }
        __syncthreads();
    }
    if (tid == 0)
        part[(size_t)o * 6 + b * 3 + bx] = make_float2(sh[0], sh2[0]);
}

// ==== K6: final BN+ReLU+AvgPool ============================================
__global__ void bn_avg_final_kernel(const float* __restrict__ x,
                                    const float2* __restrict__ part,
                                    const float* __restrict__ g,
                                    const float* __restrict__ bb,
                                    float* __restrict__ out,
                                    int B, int C, int W, int nW, int NCH) {
    int idx = blockIdx.x * blockDim.x + threadIdx.x;
    int N = B * C * nW;
    if (idx >= N) return;
    int j = idx % nW; int r = idx / nW;
    int c = r % C; int b = r / C;
    double s = 0.0, s2 = 0.0;
    for (int i = 0; i < NCH; ++i) {
        float2 p = part[(size_t)c * NCH + i];
        s += p.x; s2 += p.y;
    }
    double cnt = (double)B * W;
    double mean = s / cnt;
    double var = s2 / cnt - mean * mean;
    float rstd = (float)(1.0 / sqrt(var + 1e-5));
    float meanf = (float)mean, gg = g[c], bo = bb[c];
    const float* xb = x + ((long long)b * C + c) * W + j * 56;
    float acc = 0.f;
    for (int i = 0; i < 56; ++i) {
        float yn = (xb[i] - meanf) * rstd * gg + bo;
        acc += fmaxf(yn, 0.f);
    }
    out[idx] = acc * (1.f / 56.f);
}

// ---------------------------------------------------------------------------
extern "C" void kernel_launch(void* const* d_in, const int* in_sizes, int n_in,
                              void* d_out, int out_size, void* d_ws, size_t ws_size,
                              hipStream_t stream) {
    const float* x   = (const float*)d_in[0];
    const float* qw0 = (const float*)d_in[1];
    const float* kw0 = (const float*)d_in[2];
    const float* vw0 = (const float*)d_in[3];
    const float* ea0 = (const float*)d_in[4];
    const float* eb0 = (const float*)d_in[5];
    const float* em0 = (const float*)d_in[6];
    const float* g0  = (const float*)d_in[7];
    const float* b0  = (const float*)d_in[8];
    const float* qw1 = (const float*)d_in[9];
    const float* kw1 = (const float*)d_in[10];
    const float* vw1 = (const float*)d_in[11];
    const float* ea1 = (const float*)d_in[12];
    const float* eb1 = (const float*)d_in[13];
    const float* em1 = (const float*)d_in[14];
    const float* g1  = (const float*)d_in[15];
    const float* b1  = (const float*)d_in[16];
    const float* qw2 = (const float*)d_in[17];
    const float* kw2 = (const float*)d_in[18];
    const float* vw2 = (const float*)d_in[19];
    const float* ea2 = (const float*)d_in[20];
    const float* eb2 = (const float*)d_in[21];
    const float* em2 = (const float*)d_in[22];
    const float* g2  = (const float*)d_in[23];
    const float* b2  = (const float*)d_in[24];
    float* outp = (float*)d_out;
    (void)ws_size; (void)in_sizes; (void)n_in; (void)out_size;

    float* ws = (float*)d_ws;
    size_t off = 0;
    auto alloc = [&](size_t n) { float* p = ws + off; off += (n + 63) & ~(size_t)63; return p; };

    float* part0  = alloc(64 * 188 * 2);
    float* h0raw  = alloc(2 * 64 * 6000);
    float* G1     = alloc(64 * 64);
    float* Wy1    = alloc(512 * 64);
    float* embs1  = alloc(64);
    float* Wcat2  = alloc(192 * 128);
    float* attn1  = alloc(2 * 10 * 6000);
    float* ybuf   = alloc(2 * 512 * 6000);
    float* part1  = alloc(128 * 48 * 2);
    float* h1raw  = alloc(2 * 128 * 1500);
    float* qk2    = alloc(2 * 1500 * 32);
    float* z2     = alloc(2 * 160 * 1500);
    float* part2  = alloc(16 * 6 * 2);
    float* s2     = alloc(2 * 16 * 750);

    auto grid = [](int n) { return (n + TPB - 1) / TPB; };

    // K1: stage0 + weight prep
    {
        dim3 g(102, 2, 2);
        stage0_kernel<<<g, TPB, 0, stream>>>(x,
            qw0, kw0, vw0, ea0, eb0, em0,
            qw1, kw1, vw1, ea1, eb1, em1,
            qw2, kw2, vw2, ea2, eb2, em2,
            h0raw, (float2*)part0, G1, Wy1, embs1, Wcat2);
    }
    // K2a: stage1 attention
    {
        dim3 g(24, 4, 2);
        attn1_kernel<<<g, TPB, 0, stream>>>(G1, h0raw, (const float2*)part0,
            g0, b0, attn1);
    }
    // K2b: y-GEMM
    {
        dim3 g(47, 4, 2);
        gemm_y_kernel<<<g, TPB, 0, stream>>>(Wy1, h0raw, (const float2*)part0,
            g0, b0, ybuf);
    }
    // K3: combine1
    {
        dim3 g(24, 256);
        combine1_kernel<<<g, TPB, 0, stream>>>(ybuf, attn1, embs1,
            h1raw, (float2*)part1);
    }
    // K4: stage2 GEMM
    {
        dim3 g(12, 2, 2);
        gemm2_kernel<<<g, TPB, 0, stream>>>(Wcat2, h1raw,
            (const float2*)part1, g1, b1, qk2, z2);
    }
    // K5: stage2 attn+combine+stats
    {
        dim3 g(3, 32);
        attn_combine2_kernel<<<g, TPB, 0, stream>>>(qk2, z2, s2, (float2*)part2);
    }
    // K6: final
    bn_avg_final_kernel<<<grid(2 * 16 * 13), TPB, 0, stream>>>(s2,
        (const float2*)part2, g2, b2, outp, 2, 16, 750, 13, 6);
}

// Round 13
// 257.237 us; speedup vs baseline: 1.0959x; 1.0959x over previous
//
#include <hip/hip_runtime.h>
#include <math.h>

// ---------------------------------------------------------------------------
// EEG StandAlone Attention stem, fully fused. (Round-8 configuration — best
// measured at 257.7 us; rounds 9-12's merge/factorization experiments were
// all neutral or regressions, reverted.)
// Stage 0 (Cin=1): score = c0*x*x_shift -> softmax -> outer product; analytic
//   BN stats; subsampled pre-BN h0raw.
// Stage 1: G = qw.kw^T trick (attn_v4, no qk buffer). Value GEMM v4:
//   wave-uniform A rows via readfirstlane -> s_load, lanes = n-cols,
//   B = attn*BN(x) built in LDS; split-K=4 -> vreduce.
// Stage 2: qk+z GEMM (BN fused) -> attn -> combine+stats -> final avgpool.
// 11 launches.
// ---------------------------------------------------------------------------

#define TPB 256

// ---- stage0 prep: c0 = dot(qw,kw), vweff[5][64] ----------------------------
__global__ void prep0_kernel(const float* __restrict__ ea,   // [64,1]
                             const float* __restrict__ eb,   // [64,5]
                             const float* __restrict__ em,   // [4,64]
                             const float* __restrict__ qw,   // [1,64]
                             const float* __restrict__ kw_,  // [1,64]
                             const float* __restrict__ vw,   // [4,1,64]
                             float* __restrict__ par) {      // [0]=c0, [1+t*64+o]
    const int M4 = 4, Co = 64, kw = 5;
    __shared__ float la[4];
    __shared__ float lb[20];
    __shared__ float embs[20];
    int tid = threadIdx.x;
    if (tid < 64) {
        float p = qw[tid] * kw_[tid];
#pragma unroll
        for (int d = 1; d < 64; d <<= 1) p += __shfl_xor(p, d, 64);
        if (tid == 0) par[0] = p;
    }
    if (tid >= 64 && tid < 64 + M4) {
        int m = tid - 64;
        float s = 0.f;
        for (int o = 0; o < Co; ++o) s += em[m * Co + o] * ea[o];
        la[m] = s;
    }
    if (tid >= 128 && tid < 128 + M4 * kw) {
        int r = tid - 128;
        int m = r / kw, l = r % kw;
        float s = 0.f;
        for (int o = 0; o < Co; ++o) s += em[m * Co + o] * eb[o * kw + l];
        lb[m * kw + l] = s;
    }
    __syncthreads();
    if (tid < 5) {
        float lg[4];
        float mx = -1e30f;
        for (int m = 0; m < M4; ++m) {
            lg[m] = la[m] + lb[m * kw + tid];
            mx = fmaxf(mx, lg[m]);
        }
        float sum = 0.f;
        for (int m = 0; m < M4; ++m) { lg[m] = expf(lg[m] - mx); sum += lg[m]; }
        float inv = 1.f / sum;
        for (int m = 0; m < M4; ++m) embs[tid * 4 + m] = lg[m] * inv;
    }
    __syncthreads();
    for (int e = tid; e < 5 * 64; e += blockDim.x) {
        int t = e / 64, o = e - t * 64;
        float s = 0.f;
        for (int m = 0; m < M4; ++m) s += embs[t * 4 + m] * vw[m * 64 + o];
        par[1 + e] = s;
    }
}

// ---- stage0: fused score/softmax/value; analytic stats ---------------------
__global__ void attn_out0_kernel(const float* __restrict__ x,   // [2][8][3000]
                                 const float* __restrict__ par, // c0 + vweff
                                 float* __restrict__ h0raw,     // [2][64][6000]
                                 float2* __restrict__ part0) {  // [64][188]
    __shared__ float wsh[5][256];
    __shared__ float vsh[5 * 64];
    __shared__ float wred[4][20];
    __shared__ float wfin[20];
    int tid = threadIdx.x;
    int b = blockIdx.y;
    int oz = blockIdx.z;
    int n0 = blockIdx.x * 256;
    int n = n0 + tid;
    for (int i = tid; i < 320; i += 256) vsh[i] = par[1 + i];
    float c0 = par[0];
    float warr[5];
    if (n < 24000) {
        int h = n / 3000, w = n - h * 3000;
        const float* xr = x + b * 24000 + h * 3000;
        float xc = xr[w];
        float xs[5], s[5];
#pragma unroll
        for (int t = 0; t < 5; ++t) {
            int col = w + t - 2;
            xs[t] = (col >= 0 && col < 3000) ? xr[col] : 0.f;
            s[t] = c0 * xc * xs[t];
        }
        float mx = s[0];
#pragma unroll
        for (int t = 1; t < 5; ++t) mx = fmaxf(mx, s[t]);
        float sum = 0.f;
#pragma unroll
        for (int t = 0; t < 5; ++t) { s[t] = expf(s[t] - mx); sum += s[t]; }
        float inv = 1.f / sum;
#pragma unroll
        for (int t = 0; t < 5; ++t) warr[t] = s[t] * inv * xs[t];
    } else {
#pragma unroll
        for (int t = 0; t < 5; ++t) warr[t] = 0.f;
    }
#pragma unroll
    for (int t = 0; t < 5; ++t) wsh[t][tid] = warr[t];
    float p[20];
#pragma unroll
    for (int t = 0; t < 5; ++t) p[t] = warr[t];
    {
        int k = 5;
#pragma unroll
        for (int t = 0; t < 5; ++t)
#pragma unroll
            for (int t2 = t; t2 < 5; ++t2) p[k++] = warr[t] * warr[t2];
    }
#pragma unroll
    for (int d = 1; d < 64; d <<= 1)
#pragma unroll
        for (int i = 0; i < 20; ++i) p[i] += __shfl_xor(p[i], d, 64);
    if ((tid & 63) == 0)
#pragma unroll
        for (int i = 0; i < 20; ++i) wred[tid >> 6][i] = p[i];
    __syncthreads();
    if (tid < 20)
        wfin[tid] = wred[0][tid] + wred[1][tid] + wred[2][tid] + wred[3][tid];
    __syncthreads();
    int jq = tid & 63, og = tid >> 6;
    int nq = n0 + jq * 4;
    int h = nq / 3000, w0 = nq - h * 3000;
    bool st = (nq < 24000) && ((h & 1) == 0);
    float wq[5][4];
#pragma unroll
    for (int t = 0; t < 5; ++t)
#pragma unroll
        for (int j = 0; j < 4; ++j) wq[t][j] = wsh[t][jq * 4 + j];
    int obase = oz * 32 + og * 8;
    for (int oi = 0; oi < 8; ++oi) {
        int o = obase + oi;
        float4 v = make_float4(0.f, 0.f, 0.f, 0.f);
#pragma unroll
        for (int t = 0; t < 5; ++t) {
            float vo = vsh[t * 64 + o];
            v.x = fmaf(wq[t][0], vo, v.x);
            v.y = fmaf(wq[t][1], vo, v.y);
            v.z = fmaf(wq[t][2], vo, v.z);
            v.w = fmaf(wq[t][3], vo, v.w);
        }
        if (st) {
            size_t base = ((size_t)b * 64 + o) * 6000 + (h >> 1) * 1500 + (w0 >> 1);
            *(float2*)&h0raw[base] = make_float2(v.x, v.z);
        }
    }
    if (tid < 32) {
        int o = oz * 32 + tid;
        float vt[5];
#pragma unroll
        for (int t = 0; t < 5; ++t) vt[t] = vsh[t * 64 + o];
        float s = 0.f, s2 = 0.f;
#pragma unroll
        for (int t = 0; t < 5; ++t) s = fmaf(vt[t], wfin[t], s);
        int k = 5;
#pragma unroll
        for (int t = 0; t < 5; ++t)
#pragma unroll
            for (int t2 = t; t2 < 5; ++t2) {
                float coef = (t == t2) ? vt[t] * vt[t] : 2.f * vt[t] * vt[t2];
                s2 = fmaf(coef, wfin[k], s2);
                ++k;
            }
        int chunk = b * gridDim.x + blockIdx.x;
        part0[(size_t)o * 188 + chunk] = make_float2(s, s2);
    }
}

// ---- stage1 prep: G1[64][64]=qw.kw^T, Av1[640][128]; finalize mr0 ----------
__global__ void prep_stage1_kernel(const float* __restrict__ ea,  // [128,2]
                                   const float* __restrict__ eb,  // [128,5]
                                   const float* __restrict__ em,  // [4,128]
                                   const float* __restrict__ qw,  // [64,128]
                                   const float* __restrict__ kw_, // [64,128]
                                   const float* __restrict__ vw,  // [4,64,128]
                                   float* __restrict__ G,         // [64][64]
                                   float* __restrict__ Av,        // [640][128]
                                   const float2* __restrict__ part0,
                                   float* __restrict__ mr0) {
    const int M4 = 4, Co = 128, kh = 2, kw = 5, Cin = 64;
    __shared__ float la[8];
    __shared__ float lb[20];
    __shared__ float embs[40];
    int tid = threadIdx.x;
    if (blockIdx.x == 0 && tid < 64) {
        double s = 0.0, s2 = 0.0;
        for (int i = 0; i < 188; ++i) {
            float2 p = part0[(size_t)tid * 188 + i];
            s += p.x; s2 += p.y;
        }
        double mean = s / 48000.0;
        double var = s2 / 48000.0 - mean * mean;
        mr0[tid] = (float)mean;
        mr0[64 + tid] = (float)(1.0 / sqrt(var + 1e-5));
    }
    if (tid < M4 * kh) {
        int m = tid / kh, k = tid % kh;
        float s = 0.f;
        for (int o = 0; o < Co; ++o) s += em[m * Co + o] * ea[o * kh + k];
        la[tid] = s;
    }
    if (tid >= 64 && tid < 64 + M4 * kw) {
        int r = tid - 64;
        int m = r / kw, l = r % kw;
        float s = 0.f;
        for (int o = 0; o < Co; ++o) s += em[m * Co + o] * eb[o * kw + l];
        lb[r] = s;
    }
    __syncthreads();
    if (tid < 10) {
        int k = tid / kw, l = tid % kw;
        float lg[4];
        float mx = -1e30f;
        for (int m = 0; m < M4; ++m) {
            lg[m] = la[m * kh + k] + lb[m * kw + l];
            mx = fmaxf(mx, lg[m]);
        }
        float sum = 0.f;
        for (int m = 0; m < M4; ++m) { lg[m] = expf(lg[m] - mx); sum += lg[m]; }
        float inv = 1.f / sum;
        for (int m = 0; m < M4; ++m) embs[tid * 4 + m] = lg[m] * inv;
    }
    __syncthreads();
    const int TOTG = 64 * 64;
    const int TOT2 = 640 * 128;
    int nth = gridDim.x * blockDim.x;
    for (int e = blockIdx.x * blockDim.x + tid; e < TOTG + TOT2; e += nth) {
        if (e < TOTG) {
            int c = e >> 6, c2 = e & 63;
            float s = 0.f;
            for (int o = 0; o < 128; ++o)
                s = fmaf(qw[c * 128 + o], kw_[c2 * 128 + o], s);
            G[e] = s;
        } else {
            int e2 = e - TOTG;
            int k = e2 / Co, o = e2 - k * Co;
            int c = k / 10, t = k - c * 10;
            float val = 0.f;
            for (int m = 0; m < M4; ++m)
                val += embs[t * 4 + m] * vw[(m * Cin + c) * Co + o];
            Av[e2] = val;
        }
    }
}

// ---- stage2 prep: Wcat2; finalize mr1 --------------------------------------
__global__ void prep_wcat_kernel(const float* __restrict__ ea,
                                 const float* __restrict__ eb,
                                 const float* __restrict__ em,
                                 const float* __restrict__ qw,
                                 const float* __restrict__ kw_,
                                 const float* __restrict__ vw,
                                 float* __restrict__ Wcat,
                                 int Co, int kh, int kw, int Cin,
                                 const float2* __restrict__ part,
                                 float* __restrict__ mr,
                                 int Cprev, int NCH, int count) {
    const int M4 = 4;
    __shared__ float la[8];
    __shared__ float lb[20];
    __shared__ float embs[40];
    int K = kh * kw;
    int tid = threadIdx.x;
    if (blockIdx.x == 0 && tid < Cprev) {
        double s = 0.0, s2 = 0.0;
        for (int i = 0; i < NCH; ++i) {
            float2 p = part[(size_t)tid * NCH + i];
            s += p.x; s2 += p.y;
        }
        double mean = s / count;
        double var = s2 / count - mean * mean;
        mr[tid] = (float)mean;
        mr[Cprev + tid] = (float)(1.0 / sqrt(var + 1e-5));
    }
    if (tid < M4 * kh) {
        int m = tid / kh, k = tid % kh;
        float s = 0.f;
        for (int o = 0; o < Co; ++o) s += em[m * Co + o] * ea[o * kh + k];
        la[tid] = s;
    }
    if (tid >= 64 && tid < 64 + M4 * kw) {
        int r = tid - 64;
        int m = r / kw, l = r % kw;
        float s = 0.f;
        for (int o = 0; o < Co; ++o) s += em[m * Co + o] * eb[o * kw + l];
        lb[r] = s;
    }
    __syncthreads();
    if (tid < K) {
        int k = tid / kw, l = tid % kw;
        float lg[4];
        float mx = -1e30f;
        for (int m = 0; m < M4; ++m) {
            lg[m] = la[m * kh + k] + lb[m * kw + l];
            mx = fmaxf(mx, lg[m]);
        }
        float sum = 0.f;
        for (int m = 0; m < M4; ++m) { lg[m] = expf(lg[m] - mx); sum += lg[m]; }
        float inv = 1.f / sum;
        for (int m = 0; m < M4; ++m) embs[tid * 4 + m] = lg[m] * inv;
    }
    __syncthreads();
    int Mtot = (2 + K) * Co;
    long long total = (long long)Mtot * Cin;
    for (long long e = (long long)blockIdx.x * blockDim.x + tid; e < total;
         e += (long long)gridDim.x * blockDim.x) {
        int m = (int)(e / Cin);
        int c = (int)(e - (long long)m * Cin);
        float val;
        if (m < Co) {
            val = qw[c * Co + m];
        } else if (m < 2 * Co) {
            val = kw_[c * Co + (m - Co)];
        } else {
            int mz = m - 2 * Co;
            int t = mz / Co;
            int o = mz - t * Co;
            val = 0.f;
            for (int mm = 0; mm < M4; ++mm)
                val += embs[t * 4 + mm] * vw[(mm * Cin + c) * Co + o];
        }
        Wcat[e] = val;
    }
}

// ---- stage1 attn v4: u = G^T.xbn in-LDS, 10-tap scores, softmax ------------
__global__ void attn_v4_kernel(const float* __restrict__ G,     // [64][64]
                               const float* __restrict__ xraw,  // [b][64][6000]
                               const float* __restrict__ mr,
                               const float* __restrict__ g,
                               const float* __restrict__ bb,
                               float* __restrict__ attn) {      // [b][10][6000]
    __shared__ float xw[64][2][68];
    __shared__ float gbuf[64][64];   // Gs, then reused as us[c'][j]
    __shared__ float ssh[64][12];
    __shared__ float scb[64], sfb[64];
    int tid = threadIdx.x;
    int chunk = blockIdx.x;
    int ho = blockIdx.y;
    int b = blockIdx.z;
    int wo0 = chunk * 64;
    if (tid < 64) {
        float sc = mr[64 + tid] * g[tid];
        scb[tid] = sc;
        sfb[tid] = bb[tid] - mr[tid] * sc;
    }
    for (int e = tid; e < 4096; e += 256)
        gbuf[e >> 6][e & 63] = G[e];
    __syncthreads();
    for (int e = tid; e < 64 * 136; e += 256) {
        int c = e / 136;
        int r2 = e - c * 136;
        int r = r2 / 68, jj = r2 - r * 68;
        int row = ho - 1 + r;
        int col = wo0 + jj - 2;
        float v = 0.f;
        if (row >= 0 && col >= 0 && col < 1500) {
            float xv = xraw[((size_t)b * 64 + c) * 6000 + row * 1500 + col];
            v = fmaxf(fmaf(xv, scb[c], sfb[c]), 0.f);
        }
        xw[c][r][jj] = v;
    }
    __syncthreads();
    int j = tid & 63, cg = tid >> 6;
    float ul[16];
#pragma unroll
    for (int i = 0; i < 16; ++i) ul[i] = 0.f;
    for (int c = 0; c < 64; ++c) {
        float xv = xw[c][1][j + 2];
        float4 g0 = *(const float4*)&gbuf[c][cg * 16 + 0];
        float4 g1 = *(const float4*)&gbuf[c][cg * 16 + 4];
        float4 g2 = *(const float4*)&gbuf[c][cg * 16 + 8];
        float4 g3 = *(const float4*)&gbuf[c][cg * 16 + 12];
        ul[0]  = fmaf(g0.x, xv, ul[0]);  ul[1]  = fmaf(g0.y, xv, ul[1]);
        ul[2]  = fmaf(g0.z, xv, ul[2]);  ul[3]  = fmaf(g0.w, xv, ul[3]);
        ul[4]  = fmaf(g1.x, xv, ul[4]);  ul[5]  = fmaf(g1.y, xv, ul[5]);
        ul[6]  = fmaf(g1.z, xv, ul[6]);  ul[7]  = fmaf(g1.w, xv, ul[7]);
        ul[8]  = fmaf(g2.x, xv, ul[8]);  ul[9]  = fmaf(g2.y, xv, ul[9]);
        ul[10] = fmaf(g2.z, xv, ul[10]); ul[11] = fmaf(g2.w, xv, ul[11]);
        ul[12] = fmaf(g3.x, xv, ul[12]); ul[13] = fmaf(g3.y, xv, ul[13]);
        ul[14] = fmaf(g3.z, xv, ul[14]); ul[15] = fmaf(g3.w, xv, ul[15]);
    }
    __syncthreads();
#pragma unroll
    for (int i = 0; i < 16; ++i) gbuf[cg * 16 + i][j] = ul[i];
    __syncthreads();
    int t0 = cg, t1 = cg + 4, t2 = cg + 8;
    int dk0 = t0 / 5, dl0 = t0 % 5;
    int dk1 = t1 / 5, dl1 = t1 % 5;
    int dk2 = (t2 < 10) ? 1 : 0, dl2 = (t2 < 10) ? (t2 - 5) : 0;
    float s0 = 0.f, s1 = 0.f, s2v = 0.f;
    for (int c = 0; c < 64; ++c) {
        float uv = gbuf[c][j];
        s0 = fmaf(uv, xw[c][dk0][j + dl0], s0);
        s1 = fmaf(uv, xw[c][dk1][j + dl1], s1);
        if (t2 < 10) s2v = fmaf(uv, xw[c][dk2][j + dl2], s2v);
    }
    ssh[j][t0] = s0;
    ssh[j][t1] = s1;
    if (t2 < 10) ssh[j][t2] = s2v;
    __syncthreads();
    if (tid < 64 && wo0 + tid < 1500) {
        float sc[10];
        float mx = -1e30f;
#pragma unroll
        for (int t = 0; t < 10; ++t) { sc[t] = ssh[tid][t]; mx = fmaxf(mx, sc[t]); }
        float sum = 0.f;
#pragma unroll
        for (int t = 0; t < 10; ++t) { sc[t] = expf(sc[t] - mx); sum += sc[t]; }
        float inv = 1.f / sum;
        int n = ho * 1500 + wo0 + tid;
#pragma unroll
        for (int t = 0; t < 10; ++t)
            attn[((size_t)b * 10 + t) * 6000 + n] = sc[t] * inv;
    }
}

// ---- value GEMM v4: wave-uniform A via s_load, lanes = n-cols, SK=4 --------
__launch_bounds__(256)
__global__ void vgemm_kernel(const float* __restrict__ Av,   // [640][128]
                             const float* __restrict__ xraw, // [b][64][6000]
                             const float* __restrict__ attn, // [b][10][6000]
                             const float* __restrict__ mr,
                             const float* __restrict__ g,
                             const float* __restrict__ bb,
                             float* __restrict__ partial) {  // [4][2][128][6000]
    __shared__ float Bs[20][64];
    __shared__ float xw[16][2][68];
    __shared__ float att_s[10][64];
    __shared__ float scl[16], sfl[16];
    int tid = threadIdx.x;
    int nt = blockIdx.x;            // 0..95
    int ho = nt / 24, chunk = nt - ho * 24;
    int wo0 = chunk * 64;
    int sk = blockIdx.y;            // 0..3
    int b = blockIdx.z;
    int c_base = sk * 16;
    int lane = tid & 63;
    int wq = tid >> 6;
    int wqu = __builtin_amdgcn_readfirstlane(wq);
    if (tid < 16) {
        int c = c_base + tid;
        float sc = mr[64 + c] * g[c];
        scl[tid] = sc;
        sfl[tid] = bb[c] - mr[c] * sc;
    }
    __syncthreads();
    for (int e = tid; e < 16 * 136; e += 256) {
        int c = e / 136;
        int r2 = e - c * 136;
        int r = r2 / 68, jj = r2 - r * 68;
        int row = ho - 1 + r;
        int col = wo0 + jj - 2;
        float v = 0.f;
        if (row >= 0 && col >= 0 && col < 1500) {
            float xv = xraw[((size_t)b * 64 + c_base + c) * 6000 + row * 1500 + col];
            v = fmaxf(fmaf(xv, scl[c], sfl[c]), 0.f);
        }
        xw[c][r][jj] = v;
    }
    for (int e = tid; e < 640; e += 256) {
        int t = e >> 6, jj = e & 63;
        int col = wo0 + jj;
        att_s[t][jj] = (col < 1500)
            ? attn[((size_t)b * 10 + t) * 6000 + ho * 1500 + col] : 0.f;
    }
    __syncthreads();
    float acc[32];
#pragma unroll
    for (int i = 0; i < 32; ++i) acc[i] = 0.f;
    int dk = wq & 1;
    int clh = wq >> 1;
    for (int kc = 0; kc < 8; ++kc) {
#pragma unroll
        for (int it = 0; it < 5; ++it)
            Bs[wq * 5 + it][lane] =
                xw[kc * 2 + clh][dk][lane + it] * att_s[dk * 5 + it][lane];
        __syncthreads();
        const float* ap0 = Av + (size_t)(c_base * 10 + kc * 20) * 128 + wqu * 32;
#pragma unroll
        for (int kk = 0; kk < 20; ++kk) {
            float bv = Bs[kk][lane];
            const float* ap = ap0 + kk * 128;
#pragma unroll
            for (int i = 0; i < 32; ++i)
                acc[i] = fmaf(ap[i], bv, acc[i]);
        }
        __syncthreads();
    }
    int wo = wo0 + lane;
    if (wo < 1500) {
        int n = ho * 1500 + wo;
#pragma unroll
        for (int i = 0; i < 32; ++i) {
            int o = wq * 32 + i;
            partial[(((size_t)sk * 2 + b) * 128 + o) * 6000 + n] = acc[i];
        }
    }
}

// ---- vreduce: sum 4 partials -> subsampled h1raw + BN stats partials -------
__global__ void vreduce_kernel(const float* __restrict__ partial, // [4][2][128][6000]
                               float* __restrict__ h1raw,         // [2][128][1500]
                               float2* __restrict__ part1) {      // [128][12]
    int tid = threadIdx.x;
    int by = blockIdx.y;
    int b = by >> 7, o = by & 127;
    int n = blockIdx.x * 1024 + tid * 4;
    float4 v = make_float4(0.f, 0.f, 0.f, 0.f);
    if (n < 6000) {
#pragma unroll
        for (int sk = 0; sk < 4; ++sk) {
            float4 p = *(const float4*)&partial[(((size_t)sk * 2 + b) * 128 + o) * 6000 + n];
            v.x += p.x; v.y += p.y; v.z += p.z; v.w += p.w;
        }
        int ho = n / 1500, wo = n - ho * 1500;
        if ((ho & 1) == 0) {
            size_t base = ((size_t)b * 128 + o) * 1500 + (ho >> 1) * 750 + (wo >> 1);
            *(float2*)&h1raw[base] = make_float2(v.x, v.z);
        }
    }
    float s = v.x + v.y + v.z + v.w;
    float s2 = v.x * v.x + v.y * v.y + v.z * v.z + v.w * v.w;
    __shared__ float sh[TPB], sh2[TPB];
    sh[tid] = s; sh2[tid] = s2;
    __syncthreads();
    for (int st = TPB / 2; st > 0; st >>= 1) {
        if (tid < st) { sh[tid] += sh[tid + st]; sh2[tid] += sh2[tid + st]; }
        __syncthreads();
    }
    if (tid == 0)
        part1[(size_t)o * 12 + b * 6 + blockIdx.x] = make_float2(sh[0], sh2[0]);
}

// ---- GEMM with BN+ReLU fused into B-staging (stage 2) ----------------------
__launch_bounds__(256, 4)
__global__ void gemm_qkbn_kernel(const float* __restrict__ A,
                                 const float* __restrict__ xraw,
                                 const float* __restrict__ mr,
                                 const float* __restrict__ g,
                                 const float* __restrict__ bb,
                                 float* __restrict__ qk,
                                 float* __restrict__ z,
                                 int M, int N, int K, int twoCo) {
    __shared__ float As[32][132];
    __shared__ float Bs[32][132];
    __shared__ float scale[128], shift[128];
    int tid = threadIdx.x;
    int b = blockIdx.z;
    int m0 = blockIdx.y * 128, n0 = blockIdx.x * 128;
    int Mz = M - twoCo;
    float acc[8][8] = {{0.f}};
    int am = tid >> 1, ak = (tid & 1) * 16;
    int bk = tid >> 3, bn = (tid & 7) * 16;
    int tm = tid & 15, tn = tid >> 4;
    for (int c = tid; c < K; c += 256) {
        float sc = mr[K + c] * g[c];
        scale[c] = sc;
        shift[c] = bb[c] - mr[c] * sc;
    }
    __syncthreads();
    for (int k0 = 0; k0 < K; k0 += 32) {
        {
            int mA = m0 + am;
            const float* Ap = A + (size_t)mA * K + k0 + ak;
#pragma unroll
            for (int q = 0; q < 4; ++q) {
                float4 v = (mA < M) ? *(const float4*)(Ap + q * 4)
                                    : make_float4(0.f, 0.f, 0.f, 0.f);
                int kk = ak + q * 4;
                As[kk + 0][am] = v.x;
                As[kk + 1][am] = v.y;
                As[kk + 2][am] = v.z;
                As[kk + 3][am] = v.w;
            }
        }
        {
            int c = k0 + bk;
            float sc = scale[c], sf = shift[c];
            const float* Xp = xraw + ((size_t)b * K + c) * N + n0 + bn;
            if (n0 + 128 <= N) {
#pragma unroll
                for (int q = 0; q < 4; ++q) {
                    float4 v = *(const float4*)(Xp + q * 4);
                    v.x = fmaxf(fmaf(v.x, sc, sf), 0.f);
                    v.y = fmaxf(fmaf(v.y, sc, sf), 0.f);
                    v.z = fmaxf(fmaf(v.z, sc, sf), 0.f);
                    v.w = fmaxf(fmaf(v.w, sc, sf), 0.f);
                    *(float4*)&Bs[bk][bn + q * 4] = v;
                }
            } else {
#pragma unroll
                for (int q = 0; q < 16; ++q) {
                    int n = n0 + bn + q;
                    Bs[bk][bn + q] = (n < N) ? fmaxf(fmaf(Xp[q], sc, sf), 0.f) : 0.f;
                }
            }
        }
        __syncthreads();
#pragma unroll 8
        for (int k = 0; k < 32; ++k) {
            float4 a0 = *(const float4*)&As[k][tm * 4];
            float4 a1 = *(const float4*)&As[k][64 + tm * 4];
            float4 b0 = *(const float4*)&Bs[k][tn * 4];
            float4 b1 = *(const float4*)&Bs[k][64 + tn * 4];
            float av[8] = {a0.x, a0.y, a0.z, a0.w, a1.x, a1.y, a1.z, a1.w};
            float bv[8] = {b0.x, b0.y, b0.z, b0.w, b1.x, b1.y, b1.z, b1.w};
#pragma unroll
            for (int i = 0; i < 8; ++i)
#pragma unroll
                for (int j = 0; j < 8; ++j)
                    acc[i][j] = fmaf(av[i], bv[j], acc[i][j]);
        }
        __syncthreads();
    }
    bool fullN = (n0 + 128 <= N);
#pragma unroll
    for (int iq = 0; iq < 2; ++iq) {
        int mb = m0 + iq * 64 + tm * 4;
        if (mb >= M) continue;
        if (mb < twoCo) {
#pragma unroll
            for (int jq = 0; jq < 2; ++jq)
#pragma unroll
                for (int jj = 0; jj < 4; ++jj) {
                    int n = n0 + jq * 64 + tn * 4 + jj;
                    if (n < N) {
                        float4 v = make_float4(acc[iq * 4 + 0][jq * 4 + jj],
                                               acc[iq * 4 + 1][jq * 4 + jj],
                                               acc[iq * 4 + 2][jq * 4 + jj],
                                               acc[iq * 4 + 3][jq * 4 + jj]);
                        *(float4*)&qk[((size_t)b * N + n) * twoCo + mb] = v;
                    }
                }
        } else {
#pragma unroll
            for (int i = 0; i < 4; ++i) {
                int row = mb + i - twoCo;
                float* zp = &z[((size_t)b * Mz + row) * N];
#pragma unroll
                for (int jq = 0; jq < 2; ++jq) {
                    int nb_ = n0 + jq * 64 + tn * 4;
                    if (fullN) {
                        *(float4*)&zp[nb_] = make_float4(acc[iq * 4 + i][jq * 4 + 0],
                                                         acc[iq * 4 + i][jq * 4 + 1],
                                                         acc[iq * 4 + i][jq * 4 + 2],
                                                         acc[iq * 4 + i][jq * 4 + 3]);
                    } else {
#pragma unroll
                        for (int jj = 0; jj < 4; ++jj)
                            if (nb_ + jj < N) zp[nb_ + jj] = acc[iq * 4 + i][jq * 4 + jj];
                    }
                }
            }
        }
    }
}

// ---- attention scores + softmax (stage 2) ----------------------------------
template <int KH, int KW, int CO, int NPB>
__global__ void attn_v3_kernel(const float* __restrict__ qk,
                               float* __restrict__ attn,
                               int H, int W, int Ho, int Wo, int pt, int pl) {
    const int K = KH * KW;
    __shared__ float ssh[NPB][K];
    int tid = threadIdx.x;
    int b = blockIdx.y;
    int ln = tid / K, t = tid - ln * K;
    int Nout = Ho * Wo;
    int n = blockIdx.x * NPB + ln;
    bool active = (tid < NPB * K) && (n < Nout);
    int HWin = H * W;
    float sv = 0.f;
    if (active) {
        int ho = n / Wo, wo = n - ho * Wo;
        int row = ho + t / KW - pt, col = wo + t % KW - pl;
        if (row >= 0 && row < H && col >= 0 && col < W) {
            const float* qp = qk + ((size_t)b * HWin + ho * W + wo) * (2 * CO);
            const float* kp = qk + ((size_t)b * HWin + (size_t)row * W + col) * (2 * CO) + CO;
#pragma unroll
            for (int o = 0; o < CO; o += 4) {
                float4 q4 = *(const float4*)(qp + o);
                float4 k4 = *(const float4*)(kp + o);
                sv += q4.x * k4.x + q4.y * k4.y + q4.z * k4.z + q4.w * k4.w;
            }
        }
        ssh[ln][t] = sv;
    }
    __syncthreads();
    if (active) {
        float mx = ssh[ln][0];
#pragma unroll
        for (int tt = 1; tt < K; ++tt) mx = fmaxf(mx, ssh[ln][tt]);
        float sum = 0.f;
#pragma unroll
        for (int tt = 0; tt < K; ++tt) sum += expf(ssh[ln][tt] - mx);
        float num = expf(sv - mx);
        attn[((size_t)b * K + t) * Nout + n] = num / sum;
    }
}

// ---- stage2 combine + BN partials ------------------------------------------
template <int KH, int KW>
__global__ void combine_stats_kernel(const float* __restrict__ z,
                                     const float* __restrict__ attn,
                                     float* __restrict__ out,
                                     float2* __restrict__ part,
                                     int Co, int Mz,
                                     int H, int W, int Ho, int Wo,
                                     int pt, int pl) {
    const int K = KH * KW;
    int tid = threadIdx.x;
    int bc = blockIdx.y;
    int b = bc / Co, o = bc - b * Co;
    int Nout = Ho * Wo, Nin = H * W;
    int n = blockIdx.x * blockDim.x + tid;
    float val = 0.f;
    if (n < Nout) {
        int ho = n / Wo, wo = n - ho * Wo;
#pragma unroll
        for (int dk = 0; dk < KH; ++dk) {
            int row = ho + dk - pt;
            if (row < 0 || row >= H) continue;
#pragma unroll
            for (int dl = 0; dl < KW; ++dl) {
                int col = wo + dl - pl;
                if (col < 0 || col >= W) continue;
                int t = dk * KW + dl;
                float a = attn[((size_t)b * K + t) * Nout + n];
                float zv = z[((size_t)b * Mz + t * Co + o) * Nin + row * W + col];
                val = fmaf(a, zv, val);
            }
        }
        out[((size_t)b * Co + o) * Nout + n] = val;
    }
    __shared__ float sh[TPB], sh2[TPB];
    sh[tid] = (n < Nout) ? val : 0.f;
    sh2[tid] = (n < Nout) ? val * val : 0.f;
    __syncthreads();
    for (int st = TPB / 2; st > 0; st >>= 1) {
        if (tid < st) { sh[tid] += sh[tid + st]; sh2[tid] += sh2[tid + st]; }
        __syncthreads();
    }
    if (tid == 0) {
        int chunk = b * gridDim.x + blockIdx.x;
        part[(size_t)o * (2 * gridDim.x) + chunk] = make_float2(sh[0], sh2[0]);
    }
}

// ---- final: BN finalize + bn+relu + AvgPool(1,56) --------------------------
__global__ void bn_avg_final_kernel(const float* __restrict__ x,
                                    const float2* __restrict__ part,
                                    const float* __restrict__ g,
                                    const float* __restrict__ bb,
                                    float* __restrict__ out,
                                    int B, int C, int W, int nW, int NCH) {
    int idx = blockIdx.x * blockDim.x + threadIdx.x;
    int N = B * C * nW;
    if (idx >= N) return;
    int j = idx % nW; int r = idx / nW;
    int c = r % C; int b = r / C;
    double s = 0.0, s2 = 0.0;
    for (int i = 0; i < NCH; ++i) {
        float2 p = part[(size_t)c * NCH + i];
        s += p.x; s2 += p.y;
    }
    double cnt = (double)B * W;
    double mean = s / cnt;
    double var = s2 / cnt - mean * mean;
    float rstd = (float)(1.0 / sqrt(var + 1e-5));
    float meanf = (float)mean, gg = g[c], bo = bb[c];
    const float* xb = x + ((long long)b * C + c) * W + j * 56;
    float acc = 0.f;
    for (int i = 0; i < 56; ++i) {
        float yn = (xb[i] - meanf) * rstd * gg + bo;
        acc += fmaxf(yn, 0.f);
    }
    out[idx] = acc * (1.f / 56.f);
}

// ---------------------------------------------------------------------------
extern "C" void kernel_launch(void* const* d_in, const int* in_sizes, int n_in,
                              void* d_out, int out_size, void* d_ws, size_t ws_size,
                              hipStream_t stream) {
    const float* x   = (const float*)d_in[0];
    const float* qw0 = (const float*)d_in[1];
    const float* kw0 = (const float*)d_in[2];
    const float* vw0 = (const float*)d_in[3];
    const float* ea0 = (const float*)d_in[4];
    const float* eb0 = (const float*)d_in[5];
    const float* em0 = (const float*)d_in[6];
    const float* g0  = (const float*)d_in[7];
    const float* b0  = (const float*)d_in[8];
    const float* qw1 = (const float*)d_in[9];
    const float* kw1 = (const float*)d_in[10];
    const float* vw1 = (const float*)d_in[11];
    const float* ea1 = (const float*)d_in[12];
    const float* eb1 = (const float*)d_in[13];
    const float* em1 = (const float*)d_in[14];
    const float* g1  = (const float*)d_in[15];
    const float* b1  = (const float*)d_in[16];
    const float* qw2 = (const float*)d_in[17];
    const float* kw2 = (const float*)d_in[18];
    const float* vw2 = (const float*)d_in[19];
    const float* ea2 = (const float*)d_in[20];
    const float* eb2 = (const float*)d_in[21];
    const float* em2 = (const float*)d_in[22];
    const float* g2  = (const float*)d_in[23];
    const float* b2  = (const float*)d_in[24];
    float* outp = (float*)d_out;
    (void)ws_size; (void)in_sizes; (void)n_in; (void)out_size;

    float* ws = (float*)d_ws;
    size_t off = 0;
    auto alloc = [&](size_t n) { float* p = ws + off; off += (n + 63) & ~(size_t)63; return p; };

    float* par0   = alloc(321);
    float* part0  = alloc(64 * 188 * 2);
    float* mr0    = alloc(128);
    float* h0raw  = alloc(2 * 64 * 6000);
    float* G1     = alloc(64 * 64);
    float* Av1    = alloc(640 * 128);
    float* attn1  = alloc(2 * 10 * 6000);
    float* vpart  = alloc(4 * 2 * 128 * 6000);  // split-K=4 partials
    float* part1  = alloc(128 * 12 * 2);
    float* mr1    = alloc(256);
    float* h1raw  = alloc(2 * 128 * 1500);
    float* Wcat2  = alloc(192 * 128);
    float* qk2    = alloc(2 * 1500 * 32);
    float* z2     = alloc(2 * 160 * 1500);
    float* attn2  = alloc(2 * 10 * 750);
    float* part2  = alloc(16 * 6 * 2);
    float* s2     = alloc(2 * 16 * 750);

    auto grid = [](int n) { return (n + TPB - 1) / TPB; };

    // ======== stage 0
    prep0_kernel<<<1, TPB, 0, stream>>>(ea0, eb0, em0, qw0, kw0, vw0, par0);
    {
        dim3 g(94, 2, 2);
        attn_out0_kernel<<<g, TPB, 0, stream>>>(x, par0, h0raw, (float2*)part0);
    }
    // ======== stage 1
    prep_stage1_kernel<<<64, TPB, 0, stream>>>(ea1, eb1, em1, qw1, kw1, vw1,
        G1, Av1, (const float2*)part0, mr0);
    {
        dim3 g(24, 4, 2);   // chunk, ho, b
        attn_v4_kernel<<<g, TPB, 0, stream>>>(G1, h0raw, mr0, g0, b0, attn1);
    }
    {
        dim3 g(96, 4, 2);   // n-tiles(ho*chunk), sk, b
        vgemm_kernel<<<g, TPB, 0, stream>>>(Av1, h0raw, attn1, mr0, g0, b0, vpart);
    }
    {
        dim3 g(6, 256);
        vreduce_kernel<<<g, TPB, 0, stream>>>(vpart, h1raw, (float2*)part1);
    }
    // ======== stage 2
    prep_wcat_kernel<<<24, TPB, 0, stream>>>(ea2, eb2, em2, qw2, kw2, vw2, Wcat2,
        16, 2, 5, 128, (const float2*)part1, mr1, 128, 12, 12000);
    {
        dim3 g(12, 2, 2);
        gemm_qkbn_kernel<<<g, TPB, 0, stream>>>(Wcat2, h1raw, mr1, g1, b1,
            qk2, z2, 192, 1500, 128, 32);
    }
    {
        dim3 g(750 / 25, 2);
        attn_v3_kernel<2, 5, 16, 25><<<g, TPB, 0, stream>>>(qk2, attn2,
            2, 750, 1, 750, 0, 2);
    }
    {
        dim3 g(3, 2 * 16);
        combine_stats_kernel<2, 5><<<g, TPB, 0, stream>>>(z2, attn2, s2,
            (float2*)part2, 16, 160, 2, 750, 1, 750, 0, 2);
    }
    bn_avg_final_kernel<<<grid(2 * 16 * 13), TPB, 0, stream>>>(s2, (const float2*)part2,
        g2, b2, outp, 2, 16, 750, 13, 6);
}